// Round 3
// baseline (368.374 us; speedup 1.0000x reference)
//
#include <hip/hip_runtime.h>
#include <cmath>

typedef __bf16 bf16;
typedef __bf16 bf16x8 __attribute__((ext_vector_type(8)));
typedef __bf16 bf16x4 __attribute__((ext_vector_type(4)));
typedef __bf16 bf16x2 __attribute__((ext_vector_type(2)));
typedef float floatx4 __attribute__((ext_vector_type(4)));

#define MFMA16(A, B, C) __builtin_amdgcn_mfma_f32_16x16x32_bf16((A), (B), (C), 0, 0, 0)

// async 16B/lane global->LDS (lds dest = wave-uniform base + lane*16)
#define GLDS16(g, l)                                                   \
  __builtin_amdgcn_global_load_lds(                                    \
      (const __attribute__((address_space(1))) void*)(g),              \
      (__attribute__((address_space(3))) void*)(l), 16, 0, 0)

static __device__ __forceinline__ int pack2(float a, float b) {
  bf16x2 t;
  t[0] = (bf16)a;
  t[1] = (bf16)b;
  return __builtin_bit_cast(int, t);
}

// ---------------------------------------------------------------------------
// fused: LN1 (blocks 0..8191) + fp32->bf16 weight convert (blocks 8192..)
// ---------------------------------------------------------------------------
__global__ __launch_bounds__(256) void pre_kernel(
    const float* __restrict__ x, const float* __restrict__ g,
    const float* __restrict__ be, bf16* __restrict__ h1,
    const float* __restrict__ s0, bf16* __restrict__ d0, int n0,
    const float* __restrict__ s1, bf16* __restrict__ d1, int n1,
    const float* __restrict__ s2, bf16* __restrict__ d2, int n2,
    const float* __restrict__ s3, bf16* __restrict__ d3, int n3) {
  int bid = blockIdx.x;
  int t = threadIdx.x;
  if (bid < 8192) {
    const float* xr = x + (size_t)bid * 768;
    float v0 = xr[t], v1 = xr[t + 256], v2 = xr[t + 512];
    float s = v0 + v1 + v2;
    float s2 = v0 * v0 + v1 * v1 + v2 * v2;
#pragma unroll
    for (int o = 1; o < 64; o <<= 1) {
      s += __shfl_xor(s, o, 64);
      s2 += __shfl_xor(s2, o, 64);
    }
    __shared__ float red[8];
    int w = t >> 6, lane = t & 63;
    if (lane == 0) { red[w] = s; red[4 + w] = s2; }
    __syncthreads();
    float ts = red[0] + red[1] + red[2] + red[3];
    float ts2 = red[4] + red[5] + red[6] + red[7];
    float mean = ts * (1.0f / 768.0f);
    float var = ts2 * (1.0f / 768.0f) - mean * mean;
    float rstd = rsqrtf(var + 1e-5f);
    bf16* orow = h1 + (size_t)bid * 768;
    orow[t]       = (bf16)((v0 - mean) * rstd * g[t]       + be[t]);
    orow[t + 256] = (bf16)((v1 - mean) * rstd * g[t + 256] + be[t + 256]);
    orow[t + 512] = (bf16)((v2 - mean) * rstd * g[t + 512] + be[t + 512]);
    return;
  }
  int i = (bid - 8192) * 256 + t;
  const float* s;
  bf16* d;
  if (i < n0) { s = s0 + (size_t)i * 4; d = d0 + (size_t)i * 4; }
  else if ((i -= n0) < n1) { s = s1 + (size_t)i * 4; d = d1 + (size_t)i * 4; }
  else if ((i -= n1) < n2) { s = s2 + (size_t)i * 4; d = d2 + (size_t)i * 4; }
  else if ((i -= n2) < n3) { s = s3 + (size_t)i * 4; d = d3 + (size_t)i * 4; }
  else return;
  bf16x4 v;
  v[0] = (bf16)s[0]; v[1] = (bf16)s[1]; v[2] = (bf16)s[2]; v[3] = (bf16)s[3];
  *(bf16x4*)d = v;
}

// ---------------------------------------------------------------------------
// LayerNorm over C=768, fp32 in -> bf16 out (x1 -> h2)
// ---------------------------------------------------------------------------
__global__ __launch_bounds__(256) void ln_kernel(const float* __restrict__ x,
                                                 const float* __restrict__ g,
                                                 const float* __restrict__ be,
                                                 bf16* __restrict__ out) {
  int row = blockIdx.x;
  int t = threadIdx.x;
  const float* xr = x + (size_t)row * 768;
  float v0 = xr[t], v1 = xr[t + 256], v2 = xr[t + 512];
  float s = v0 + v1 + v2;
  float s2 = v0 * v0 + v1 * v1 + v2 * v2;
#pragma unroll
  for (int o = 1; o < 64; o <<= 1) {
    s += __shfl_xor(s, o, 64);
    s2 += __shfl_xor(s2, o, 64);
  }
  __shared__ float red[8];
  int w = t >> 6, lane = t & 63;
  if (lane == 0) { red[w] = s; red[4 + w] = s2; }
  __syncthreads();
  float ts = red[0] + red[1] + red[2] + red[3];
  float ts2 = red[4] + red[5] + red[6] + red[7];
  float mean = ts * (1.0f / 768.0f);
  float var = ts2 * (1.0f / 768.0f) - mean * mean;
  float rstd = rsqrtf(var + 1e-5f);
  bf16* orow = out + (size_t)row * 768;
  orow[t]       = (bf16)((v0 - mean) * rstd * g[t]       + be[t]);
  orow[t + 256] = (bf16)((v1 - mean) * rstd * g[t + 256] + be[t + 256]);
  orow[t + 512] = (bf16)((v2 - mean) * rstd * g[t + 512] + be[t + 512]);
}

// ---------------------------------------------------------------------------
// GEMM: C[m,n] = sum_k A[m,k]*B[n,k] (+bias)  (A:[M,K] bf16, B:[N,K] bf16)
// R3: T3+T4 pipeline. BK=32, TRIPLE-buffered LDS (48KB NJ=4 / 36KB NJ=2 ->
// still 3 blocks/CU), depth-2 prefetch, ONE raw s_barrier per K-step with
// COUNTED s_waitcnt vmcnt(NL) -- prefetch loads stay in flight across the
// barrier (never drain to 0 in steady state; the R1 failure was drain-0 +
// occupancy loss). Invariant at iter t: vmcnt(NL) proves own loads(t) done;
// barrier makes all waves' loads(t) visible AND proves all waves finished
// iter t-1 -> safe to DMA into buf[(t+2)%3]. Tail iter drains vmcnt(0).
// LDS rows are 32 elems = 4 16B-granules; slot p of row r holds k-granule
// p ^ ((r>>1)&3)  (even bank spread: 8 words/bank per wave ds_read_b128).
// XCD swizzle: flat%8 = m-stripe, n fastest.
// EP_RES_F32: out = acc + bias + resid (f32) -- used with NJ=2 for N=768.
// ---------------------------------------------------------------------------
constexpr int EP_BF16 = 0;
constexpr int EP_RES_F32 = 1;
constexpr int EP_GELU_BF16 = 2;

template <int EP, int NJ>
__global__ __launch_bounds__(256, 3) void gemm_bt(
    const bf16* __restrict__ A, const bf16* __restrict__ Bw,
    const float* __restrict__ bias, const float* __restrict__ resid,
    void* __restrict__ outp, int M, int N, int K) {
  __shared__ alignas(16) bf16 Asl[3][128 * 32];
  __shared__ alignas(16) bf16 Bsl[3][NJ * 32 * 32];
  constexpr int BB = NJ / 2;  // B-stage GLDS16 issues per wave per step
  int tid = threadIdx.x;
  int lane = tid & 63, w = tid >> 6;
  int wm = w >> 1, wn = w & 1;
  int q16 = lane & 15, quad = lane >> 4;
  int fid = blockIdx.x + gridDim.x * blockIdx.y;
  int nb = gridDim.x;
  int s = fid >> 3;
  int m0 = ((fid & 7) * (gridDim.y >> 3) + s / nb) * 128;
  int n0 = (s % nb) * (NJ * 32);

  floatx4 acc[4][NJ];
#pragma unroll
  for (int i = 0; i < 4; i++)
#pragma unroll
    for (int j = 0; j < NJ; j++) acc[i][j] = (floatx4){0.f, 0.f, 0.f, 0.f};

  // staging: 16B slot G (lane-linear per GLDS16) covers row r=G>>2, slot
  // p=G&3; slot p of row r must hold global k-granule p ^ ((r>>1)&3).
  // For lane L: r = base + (L>>2), p = L&3 -> g = (L&3) ^ ((L>>3)&3).
  int rL = lane >> 2;
  int gL = (lane & 3) ^ ((lane >> 3) & 3);
  const bf16* ag[2];
#pragma unroll
  for (int q = 0; q < 2; q++)
    ag[q] = A + (size_t)(m0 + w * 32 + q * 16 + rL) * K + gL * 8;
  const bf16* bg[BB];
#pragma unroll
  for (int q = 0; q < BB; q++)
    bg[q] = Bw + (size_t)(n0 + w * (16 * BB) + q * 16 + rL) * K + gL * 8;

  auto stage = [&](int buf) {
#pragma unroll
    for (int q = 0; q < 2; q++) {
      GLDS16(ag[q], &Asl[buf][w * 1024 + q * 512]);
      ag[q] += 32;
    }
#pragma unroll
    for (int q = 0; q < BB; q++) {
      GLDS16(bg[q], &Bsl[buf][w * (512 * BB) + q * 512]);
      bg[q] += 32;
    }
  };

  // frag read offsets: row*32 + (quad ^ ((row>>1)&3))*8; row>>1 parity of
  // wm*64+i*16+q16 reduces to (q16>>1)&3 (i*8, wm*32 are 0 mod 4)
  int sw = (q16 >> 1) & 3;
  int offA[4], offB[NJ];
#pragma unroll
  for (int i = 0; i < 4; i++)
    offA[i] = (wm * 64 + i * 16 + q16) * 32 + ((quad ^ sw) * 8);
#pragma unroll
  for (int j = 0; j < NJ; j++)
    offB[j] = (wn * 16 * NJ + j * 16 + q16) * 32 + ((quad ^ sw) * 8);

  // prologue: loads(0)->buf0, loads(1)->buf1 (2*NL outstanding)
  stage(0);
  stage(1);

  int nT = K >> 5;
  int cur = 0;
  for (int t = 0; t < nT; t++) {
    if (t < nT - 1) {
      // wait for loads(t) only; loads(t+1) stay in flight across the barrier
      if constexpr (NJ == 4) {
        asm volatile("s_waitcnt vmcnt(4)" ::: "memory");
      } else {
        asm volatile("s_waitcnt vmcnt(3)" ::: "memory");
      }
    } else {
      asm volatile("s_waitcnt vmcnt(0)" ::: "memory");
    }
    asm volatile("s_barrier" ::: "memory");
    if (t + 2 < nT) {
      int pb = cur + 2;
      if (pb >= 3) pb -= 3;
      stage(pb);  // issued before compute; 2 full phases to land
    }
    const bf16* ab = Asl[cur];
    const bf16* bb = Bsl[cur];
    bf16x8 af[4], bfr[NJ];
#pragma unroll
    for (int i = 0; i < 4; i++) af[i] = *(const bf16x8*)&ab[offA[i]];
#pragma unroll
    for (int j = 0; j < NJ; j++) bfr[j] = *(const bf16x8*)&bb[offB[j]];
#pragma unroll
    for (int i = 0; i < 4; i++)
#pragma unroll
      for (int j = 0; j < NJ; j++) acc[i][j] = MFMA16(af[i], bfr[j], acc[i][j]);
    cur = (cur == 2) ? 0 : cur + 1;
  }

  // epilogue: C/D layout col = lane&15, row = quad*4 + reg  [m89-verified]
#pragma unroll
  for (int i = 0; i < 4; i++) {
#pragma unroll
    for (int j = 0; j < NJ; j++) {
#pragma unroll
      for (int r = 0; r < 4; r++) {
        int m = m0 + wm * 64 + i * 16 + quad * 4 + r;
        int n = n0 + wn * 16 * NJ + j * 16 + q16;
        size_t idx = (size_t)m * N + n;
        float v = acc[i][j][r] + bias[n];
        if constexpr (EP == EP_BF16) {
          ((bf16*)outp)[idx] = (bf16)v;
        } else if constexpr (EP == EP_RES_F32) {
          ((float*)outp)[idx] = v + resid[idx];
        } else {
          // gelu(v) = v * sigmoid(1.59577(v + 0.044715 v^3)); exp2 form
          float u = v * (2.3022083f + 0.1029443f * v * v);
          float e = __builtin_amdgcn_exp2f(-u);
          float gv = v * __builtin_amdgcn_rcpf(1.0f + e);
          ((bf16*)outp)[idx] = (bf16)gv;
        }
      }
    }
  }
}

// ---------------------------------------------------------------------------
// Flash attention, bf16 MFMA. qkv: [B,N,3,12,64] bf16 -> out [B,N,768] bf16.
// 2-wave blocks (grid 16x96), in-register P via swapped QK^T (mfma(K,Q)),
// bf16-pair pack + 8 shfl + 4 selects per q-tile. Double-buffered K/V LDS,
// single barrier per tile. No-max softmax (|s| small, shift-invariant).
// (R2: neutral vs R0 within cross-run noise; kept for lower LDS + reg-P.)
// ---------------------------------------------------------------------------
__global__ __launch_bounds__(128, 3) void attn_kernel(const bf16* __restrict__ qkv,
                                                      bf16* __restrict__ o) {
  __shared__ alignas(16) bf16 Kl[2][32 * 64];  // [buf][key][d] swizzled, 8KB
  __shared__ alignas(16) bf16 Vt[2][64 * 40];  // [buf][d][key] swizzled, 10KB
  int tid = threadIdx.x;
  int lane = tid & 63, w = tid >> 6;  // w in {0,1}
  int q16 = lane & 15, quad = lane >> 4;
  int b = blockIdx.y / 12, h = blockIdx.y % 12;
  int qbase = blockIdx.x * 64 + w * 32;
  const int KS = 32 * 2304;

  // Q fragments (B-operand layout n=q16, k=quad*8+j), 2 q-tiles x 2 d-chunks
  bf16x8 qf[2][2];
#pragma unroll
  for (int qt = 0; qt < 2; qt++)
#pragma unroll
    for (int c = 0; c < 2; c++)
      qf[qt][c] = *(const bf16x8*)(qkv +
          (size_t)(b * 1024 + qbase + qt * 16 + q16) * 2304 + h * 64 +
          c * 32 + quad * 8);

  // K DMA: wave w stages keys w*16..w*16+15 (two 8-key chunks); lane fetches
  // the 16B chunk that lands (lane-contiguous DMA) at swizzled granule
  // key*8 + (c ^ (key&7))
  int krow = lane >> 3;
  int kchunk = (lane & 7) ^ krow;
  const bf16* kg0 = qkv + (size_t)(b * 1024 + w * 16 + krow) * 2304 + 768 +
                    h * 64 + kchunk * 8;
  const bf16* kg1 = kg0 + 8 * 2304;
  bf16* kdA[2] = {&Kl[0][w * 1024], &Kl[1][w * 1024]};

  // V staging: thread -> key kr (tid>>2), d-chunks dbase, dbase+8; swizzled
  // transpose writes (granule (d*5 + key_gran) ^ ((d>>3)&7), elem key&7)
  int kr = tid >> 2;
  int dbase = (tid & 3) * 16;
  const bf16* vgA = qkv + (size_t)(b * 1024 + kr) * 2304 + 1536 + h * 64 + dbase;
  const bf16* vgB = vgA + 8;
  int vtA[8], vtB[8];
#pragma unroll
  for (int e = 0; e < 8; e++) {
    int dA = dbase + e;
    int dB = dbase + 8 + e;
    vtA[e] = ((dA * 5 + (kr >> 3)) ^ ((dA >> 3) & 7)) * 8 + (kr & 7);
    vtB[e] = ((dB * 5 + (kr >> 3)) ^ ((dB >> 3) & 7)) * 8 + (kr & 7);
  }

  // loop-invariant LDS read offsets
  int koff[2][2];
#pragma unroll
  for (int nc = 0; nc < 2; nc++)
#pragma unroll
    for (int ck = 0; ck < 2; ck++) {
      int key = nc * 16 + q16;
      koff[nc][ck] = (key * 8 + ((ck * 4 + quad) ^ (key & 7))) * 8;
    }
  int voff[4];
#pragma unroll
  for (int dc = 0; dc < 4; dc++) {
    int d = dc * 16 + q16;
    voff[dc] = ((d * 5 + quad) ^ ((d >> 3) & 7)) * 8;
  }

  int srcLo = q16 + ((quad & 1) << 5);
  int srcHi = srcLo + 16;
  bool loH = quad < 2;

  float lsum[2] = {0.f, 0.f};
  floatx4 oacc[2][4];
#pragma unroll
  for (int qt = 0; qt < 2; qt++)
#pragma unroll
    for (int dc = 0; dc < 4; dc++) oacc[qt][dc] = (floatx4){0.f, 0.f, 0.f, 0.f};

  // prologue: stage tile 0 (K-DMA + V write), prefetch V of tile 1
  GLDS16(kg0, kdA[0]);
  GLDS16(kg1, kdA[0] + 512);
  kg0 += KS; kg1 += KS;
  bf16x8 va = *(const bf16x8*)vgA;
  bf16x8 vb = *(const bf16x8*)vgB;
  vgA += KS; vgB += KS;
#pragma unroll
  for (int e = 0; e < 8; e++) Vt[0][vtA[e]] = va[e];
#pragma unroll
  for (int e = 0; e < 8; e++) Vt[0][vtB[e]] = vb[e];
  va = *(const bf16x8*)vgA;
  vb = *(const bf16x8*)vgB;
  vgA += KS; vgB += KS;

  for (int kt = 0; kt < 32; kt++) {
    int cur = kt & 1, nxt = cur ^ 1;
    __syncthreads();  // buf[cur] staged & visible; buf[nxt] free for reuse
    if (kt < 31) {
      GLDS16(kg0, kdA[nxt]);  // in flight during compute below
      GLDS16(kg1, kdA[nxt] + 512);
      kg0 += KS; kg1 += KS;
#pragma unroll
      for (int e = 0; e < 8; e++) Vt[nxt][vtA[e]] = va[e];
#pragma unroll
      for (int e = 0; e < 8; e++) Vt[nxt][vtB[e]] = vb[e];
      if (kt < 30) {
        va = *(const bf16x8*)vgA;  // prefetch V of tile kt+2
        vb = *(const bf16x8*)vgB;
        vgA += KS; vgB += KS;
      }
    }

    bf16x8 kf[2][2];
#pragma unroll
    for (int nc = 0; nc < 2; nc++)
#pragma unroll
      for (int ck = 0; ck < 2; ck++)
        kf[nc][ck] = *(const bf16x8*)&Kl[cur][koff[nc][ck]];
    bf16x8 vf[4];
#pragma unroll
    for (int dc = 0; dc < 4; dc++) vf[dc] = *(const bf16x8*)&Vt[cur][voff[dc]];

#pragma unroll
    for (int qt = 0; qt < 2; qt++) {
      // swapped QK^T: z[r] = S[key = nc*16 + quad*4 + r][q = qt*16 + q16]
      floatx4 z0 = (floatx4){0.f, 0.f, 0.f, 0.f};
      floatx4 z1 = (floatx4){0.f, 0.f, 0.f, 0.f};
      z0 = MFMA16(kf[0][0], qf[qt][0], z0);
      z0 = MFMA16(kf[0][1], qf[qt][1], z0);
      z1 = MFMA16(kf[1][0], qf[qt][0], z1);
      z1 = MFMA16(kf[1][1], qf[qt][1], z1);
      float e0[4], e1[4];
#pragma unroll
      for (int r = 0; r < 4; r++) {
        e0[r] = __builtin_amdgcn_exp2f(z0[r] * 0.18033688011f);
        e1[r] = __builtin_amdgcn_exp2f(z1[r] * 0.18033688011f);
        lsum[qt] += e0[r] + e1[r];
      }
      int A0 = pack2(e0[0], e0[1]);
      int A1 = pack2(e0[2], e0[3]);
      int B0 = pack2(e1[0], e1[1]);
      int B1 = pack2(e1[2], e1[3]);
      int tA0 = __shfl(A0, srcLo, 64), tB0 = __shfl(B0, srcLo, 64);
      int tA1 = __shfl(A1, srcLo, 64), tB1 = __shfl(B1, srcLo, 64);
      int tA2 = __shfl(A0, srcHi, 64), tB2 = __shfl(B0, srcHi, 64);
      int tA3 = __shfl(A1, srcHi, 64), tB3 = __shfl(B1, srcHi, 64);
      union { int i[4]; bf16x8 v; } pu;
      pu.i[0] = loH ? tA0 : tB0;
      pu.i[1] = loH ? tA1 : tB1;
      pu.i[2] = loH ? tA2 : tB2;
      pu.i[3] = loH ? tA3 : tB3;
#pragma unroll
      for (int dc = 0; dc < 4; dc++)
        oacc[qt][dc] = MFMA16(pu.v, vf[dc], oacc[qt][dc]);
    }
  }

  // final: l(q16) = sum over the 4 quads (disjoint key sets), broadcast to
  // output rows q = quad*4 + r via shfl, divide, store
#pragma unroll
  for (int qt = 0; qt < 2; qt++) {
    float s = lsum[qt];
    s += __shfl_xor(s, 16, 64);
    s += __shfl_xor(s, 32, 64);
    float inv = 1.0f / s;
    bf16* op = o + (size_t)(b * 1024 + qbase + qt * 16) * 768 + h * 64;
#pragma unroll
    for (int r = 0; r < 4; r++) {
      float invr = __shfl(inv, quad * 4 + r, 64);
#pragma unroll
      for (int dc = 0; dc < 4; dc++)
        op[(size_t)(quad * 4 + r) * 768 + dc * 16 + q16] =
            (bf16)(oacc[qt][dc][r] * invr);
    }
  }
}

// ---------------------------------------------------------------------------
extern "C" void kernel_launch(void* const* d_in, const int* in_sizes, int n_in,
                              void* d_out, int out_size, void* d_ws, size_t ws_size,
                              hipStream_t stream) {
  (void)in_sizes; (void)n_in; (void)out_size; (void)ws_size;
  const float* x      = (const float*)d_in[0];
  const float* ln1_w  = (const float*)d_in[1];
  const float* ln1_b  = (const float*)d_in[2];
  const float* qkv_w  = (const float*)d_in[3];
  const float* qkv_b  = (const float*)d_in[4];
  const float* proj_w = (const float*)d_in[5];
  const float* proj_b = (const float*)d_in[6];
  const float* ln2_w  = (const float*)d_in[7];
  const float* ln2_b  = (const float*)d_in[8];
  const float* fc1_w  = (const float*)d_in[9];
  const float* fc1_b  = (const float*)d_in[10];
  const float* fc2_w  = (const float*)d_in[11];
  const float* fc2_b  = (const float*)d_in[12];

  char* ws = (char*)d_ws;
  size_t off = 0;
  auto alloc = [&](size_t bytes) {
    void* p = ws + off;
    off += (bytes + 255) & ~(size_t)255;
    return p;
  };
  bf16* wq  = (bf16*)alloc((size_t)2304 * 768 * 2);
  bf16* wp  = (bf16*)alloc((size_t)768 * 768 * 2);
  bf16* wf1 = (bf16*)alloc((size_t)3072 * 768 * 2);
  bf16* wf2 = (bf16*)alloc((size_t)768 * 3072 * 2);
  bf16* slotA = (bf16*)alloc((size_t)8192 * 768 * 2);   // h1 / ob / h2
  bf16* slotB = (bf16*)alloc((size_t)8192 * 3072 * 2);  // qkv / fc1-out
  float* x1 = (float*)alloc((size_t)8192 * 768 * 4);

  bf16* h1 = slotA;
  bf16* qkvb = slotB;
  bf16* ob = slotA;
  bf16* h2 = slotA;
  bf16* hm = slotB;

  pre_kernel<<<8192 + 6912, 256, 0, stream>>>(
      x, ln1_w, ln1_b, h1,
      qkv_w, wq, 2304 * 768 / 4, proj_w, wp, 768 * 768 / 4,
      fc1_w, wf1, 3072 * 768 / 4, fc2_w, wf2, 768 * 3072 / 4);

  gemm_bt<EP_BF16, 4><<<dim3(18, 64), 256, 0, stream>>>(
      h1, wq, qkv_b, nullptr, qkvb, 8192, 2304, 768);
  attn_kernel<<<dim3(16, 96), 128, 0, stream>>>(qkvb, ob);
  gemm_bt<EP_RES_F32, 2><<<dim3(12, 64), 256, 0, stream>>>(
      ob, wp, proj_b, x, x1, 8192, 768, 768);
  ln_kernel<<<8192, 256, 0, stream>>>(x1, ln2_w, ln2_b, h2);
  gemm_bt<EP_GELU_BF16, 4><<<dim3(24, 64), 256, 0, stream>>>(
      h2, wf1, fc1_b, nullptr, hm, 8192, 3072, 768);
  gemm_bt<EP_RES_F32, 2><<<dim3(12, 64), 256, 0, stream>>>(
      hm, wf2, fc2_b, x1, (float*)d_out, 8192, 768, 3072);
}

// Round 5
// 343.388 us; speedup vs baseline: 1.0728x; 1.0728x over previous
//
#include <hip/hip_runtime.h>
#include <cmath>

typedef __bf16 bf16;
typedef __bf16 bf16x8 __attribute__((ext_vector_type(8)));
typedef __bf16 bf16x4 __attribute__((ext_vector_type(4)));
typedef __bf16 bf16x2 __attribute__((ext_vector_type(2)));
typedef float floatx4 __attribute__((ext_vector_type(4)));

#define MFMA16(A, B, C) __builtin_amdgcn_mfma_f32_16x16x32_bf16((A), (B), (C), 0, 0, 0)

// async 16B/lane global->LDS (lds dest = wave-uniform base + lane*16)
#define GLDS16(g, l)                                                   \
  __builtin_amdgcn_global_load_lds(                                    \
      (const __attribute__((address_space(1))) void*)(g),              \
      (__attribute__((address_space(3))) void*)(l), 16, 0, 0)

static __device__ __forceinline__ int pack2(float a, float b) {
  bf16x2 t;
  t[0] = (bf16)a;
  t[1] = (bf16)b;
  return __builtin_bit_cast(int, t);
}

// ---------------------------------------------------------------------------
// fused: LN1 (blocks 0..8191) + fp32->bf16 weight convert (blocks 8192..)
// ---------------------------------------------------------------------------
__global__ __launch_bounds__(256) void pre_kernel(
    const float* __restrict__ x, const float* __restrict__ g,
    const float* __restrict__ be, bf16* __restrict__ h1,
    const float* __restrict__ s0, bf16* __restrict__ d0, int n0,
    const float* __restrict__ s1, bf16* __restrict__ d1, int n1,
    const float* __restrict__ s2, bf16* __restrict__ d2, int n2,
    const float* __restrict__ s3, bf16* __restrict__ d3, int n3) {
  int bid = blockIdx.x;
  int t = threadIdx.x;
  if (bid < 8192) {
    const float* xr = x + (size_t)bid * 768;
    float v0 = xr[t], v1 = xr[t + 256], v2 = xr[t + 512];
    float s = v0 + v1 + v2;
    float s2 = v0 * v0 + v1 * v1 + v2 * v2;
#pragma unroll
    for (int o = 1; o < 64; o <<= 1) {
      s += __shfl_xor(s, o, 64);
      s2 += __shfl_xor(s2, o, 64);
    }
    __shared__ float red[8];
    int w = t >> 6, lane = t & 63;
    if (lane == 0) { red[w] = s; red[4 + w] = s2; }
    __syncthreads();
    float ts = red[0] + red[1] + red[2] + red[3];
    float ts2 = red[4] + red[5] + red[6] + red[7];
    float mean = ts * (1.0f / 768.0f);
    float var = ts2 * (1.0f / 768.0f) - mean * mean;
    float rstd = rsqrtf(var + 1e-5f);
    bf16* orow = h1 + (size_t)bid * 768;
    orow[t]       = (bf16)((v0 - mean) * rstd * g[t]       + be[t]);
    orow[t + 256] = (bf16)((v1 - mean) * rstd * g[t + 256] + be[t + 256]);
    orow[t + 512] = (bf16)((v2 - mean) * rstd * g[t + 512] + be[t + 512]);
    return;
  }
  int i = (bid - 8192) * 256 + t;
  const float* s;
  bf16* d;
  if (i < n0) { s = s0 + (size_t)i * 4; d = d0 + (size_t)i * 4; }
  else if ((i -= n0) < n1) { s = s1 + (size_t)i * 4; d = d1 + (size_t)i * 4; }
  else if ((i -= n1) < n2) { s = s2 + (size_t)i * 4; d = d2 + (size_t)i * 4; }
  else if ((i -= n2) < n3) { s = s3 + (size_t)i * 4; d = d3 + (size_t)i * 4; }
  else return;
  bf16x4 v;
  v[0] = (bf16)s[0]; v[1] = (bf16)s[1]; v[2] = (bf16)s[2]; v[3] = (bf16)s[3];
  *(bf16x4*)d = v;
}

// ---------------------------------------------------------------------------
// LayerNorm over C=768, fp32 in -> bf16 out (x1 -> h2)
// ---------------------------------------------------------------------------
__global__ __launch_bounds__(256) void ln_kernel(const float* __restrict__ x,
                                                 const float* __restrict__ g,
                                                 const float* __restrict__ be,
                                                 bf16* __restrict__ out) {
  int row = blockIdx.x;
  int t = threadIdx.x;
  const float* xr = x + (size_t)row * 768;
  float v0 = xr[t], v1 = xr[t + 256], v2 = xr[t + 512];
  float s = v0 + v1 + v2;
  float s2 = v0 * v0 + v1 * v1 + v2 * v2;
#pragma unroll
  for (int o = 1; o < 64; o <<= 1) {
    s += __shfl_xor(s, o, 64);
    s2 += __shfl_xor(s2, o, 64);
  }
  __shared__ float red[8];
  int w = t >> 6, lane = t & 63;
  if (lane == 0) { red[w] = s; red[4 + w] = s2; }
  __syncthreads();
  float ts = red[0] + red[1] + red[2] + red[3];
  float ts2 = red[4] + red[5] + red[6] + red[7];
  float mean = ts * (1.0f / 768.0f);
  float var = ts2 * (1.0f / 768.0f) - mean * mean;
  float rstd = rsqrtf(var + 1e-5f);
  bf16* orow = out + (size_t)row * 768;
  orow[t]       = (bf16)((v0 - mean) * rstd * g[t]       + be[t]);
  orow[t + 256] = (bf16)((v1 - mean) * rstd * g[t + 256] + be[t + 256]);
  orow[t + 512] = (bf16)((v2 - mean) * rstd * g[t + 512] + be[t + 512]);
}

// ---------------------------------------------------------------------------
// GEMM: C[m,n] = sum_k A[m,k]*B[n,k] (+bias)  (A:[M,K] bf16, B:[N,K] bf16)
// 128 x (32*NJ) tile, 4 waves (each 64 x 16*NJ), BK=64, global_load_lds
// width=16 into XOR-granule-swizzled 64-elem rows (2-way ds_read, free).
// XCD swizzle: flat%8 = m-stripe, n fastest.
// EP_RES_F32: out = acc + bias + resid (f32) -- used with NJ=2 for N=768.
// (R1: explicit dbuf cost occupancy -> regressed. R3: BK=32 counted-vmcnt
// pipeline halved the phase, doubled barriers -> regressed harder. This
// 2-barrier BK=64 form at 3 blocks/CU is the measured best; frozen.)
// ---------------------------------------------------------------------------
constexpr int EP_BF16 = 0;
constexpr int EP_RES_F32 = 1;
constexpr int EP_GELU_BF16 = 2;

template <int EP, int NJ>
__global__ __launch_bounds__(256, 3) void gemm_bt(
    const bf16* __restrict__ A, const bf16* __restrict__ Bw,
    const float* __restrict__ bias, const float* __restrict__ resid,
    void* __restrict__ outp, int M, int N, int K) {
  __shared__ alignas(16) bf16 Asl[128 * 64];
  __shared__ alignas(16) bf16 Bsl[NJ * 32 * 64];
  int tid = threadIdx.x;
  int lane = tid & 63, w = tid >> 6;
  int wm = w >> 1, wn = w & 1;
  int q16 = lane & 15, quad = lane >> 4;
  int fid = blockIdx.x + gridDim.x * blockIdx.y;
  int nb = gridDim.x;
  int s = fid >> 3;
  int m0 = ((fid & 7) * (gridDim.y >> 3) + s / nb) * 128;
  int n0 = (s % nb) * (NJ * 32);

  floatx4 acc[4][NJ];
#pragma unroll
  for (int i = 0; i < 4; i++)
#pragma unroll
    for (int j = 0; j < NJ; j++) acc[i][j] = (floatx4){0.f, 0.f, 0.f, 0.f};

  // staging: chunk ca covers rows ca*8..+7; lane L -> row ca*8+(L>>3),
  // k-granule (L&7)^(L>>3)  (lands at swizzled granule ca*64+L)
  int rIn = lane >> 3;
  int cg = (lane & 7) ^ rIn;
  const bf16* ag[4];
  const bf16* bg[NJ];
#pragma unroll
  for (int q = 0; q < 4; q++)
    ag[q] = A + (size_t)(m0 + (w * 4 + q) * 8 + rIn) * K + cg * 8;
#pragma unroll
  for (int q = 0; q < NJ; q++)
    bg[q] = Bw + (size_t)(n0 + (w * NJ + q) * 8 + rIn) * K + cg * 8;
  bf16* la = &Asl[w * 2048];
  bf16* lb = &Bsl[w * NJ * 512];

  // frag read offsets: (row)*64 + ((ks*4+quad)^(row&7))*8
  int msel = q16 & 7;
  int offA[2][4], offB[2][NJ];
#pragma unroll
  for (int ks = 0; ks < 2; ks++) {
#pragma unroll
    for (int i = 0; i < 4; i++)
      offA[ks][i] = (wm * 64 + i * 16 + q16) * 64 + (((ks * 4 + quad) ^ msel)) * 8;
#pragma unroll
    for (int j = 0; j < NJ; j++)
      offB[ks][j] = (wn * 16 * NJ + j * 16 + q16) * 64 + (((ks * 4 + quad) ^ msel)) * 8;
  }

  for (int k0 = 0; k0 < K; k0 += 64) {
    __syncthreads();
#pragma unroll
    for (int q = 0; q < 4; q++) {
      GLDS16(ag[q], la + q * 512);
      ag[q] += 64;
    }
#pragma unroll
    for (int q = 0; q < NJ; q++) {
      GLDS16(bg[q], lb + q * 512);
      bg[q] += 64;
    }
    __syncthreads();
#pragma unroll
    for (int ks = 0; ks < 2; ks++) {
      bf16x8 af[4], bfr[NJ];
#pragma unroll
      for (int i = 0; i < 4; i++) af[i] = *(const bf16x8*)&Asl[offA[ks][i]];
#pragma unroll
      for (int j = 0; j < NJ; j++) bfr[j] = *(const bf16x8*)&Bsl[offB[ks][j]];
#pragma unroll
      for (int i = 0; i < 4; i++)
#pragma unroll
        for (int j = 0; j < NJ; j++) acc[i][j] = MFMA16(af[i], bfr[j], acc[i][j]);
    }
  }

  // epilogue: C/D layout col = lane&15, row = quad*4 + reg  [m89-verified]
#pragma unroll
  for (int i = 0; i < 4; i++) {
#pragma unroll
    for (int j = 0; j < NJ; j++) {
#pragma unroll
      for (int r = 0; r < 4; r++) {
        int m = m0 + wm * 64 + i * 16 + quad * 4 + r;
        int n = n0 + wn * 16 * NJ + j * 16 + q16;
        size_t idx = (size_t)m * N + n;
        float v = acc[i][j][r] + bias[n];
        if constexpr (EP == EP_BF16) {
          ((bf16*)outp)[idx] = (bf16)v;
        } else if constexpr (EP == EP_RES_F32) {
          ((float*)outp)[idx] = v + resid[idx];
        } else {
          // gelu(v) = v * sigmoid(1.59577(v + 0.044715 v^3)); exp2 form
          float u = v * (2.3022083f + 0.1029443f * v * v);
          float e = __builtin_amdgcn_exp2f(-u);
          float gv = v * __builtin_amdgcn_rcpf(1.0f + e);
          ((bf16*)outp)[idx] = (bf16)gv;
        }
      }
    }
  }
}

// ---------------------------------------------------------------------------
// Flash attention, bf16 MFMA. qkv: [B,N,3,12,64] bf16 -> out [B,N,768] bf16.
// R4: KVBLK=64 (attn is latency-chain-bound at 16% MfmaUtil / 33% VALU /
// 27% occupancy -- nothing saturated). Double work per barrier, halve the
// barrier count (32->16 tiles), double the DMA in-flight window. 4-wave
// blocks (grid 8x96 = 3 blocks/CU = 12 waves/CU), wave owns 32 queries,
// in-register P via swapped QK^T (HW-verified R2 mapping, extended to 2
// key-chunks: nc0/1 -> P-chunk 0 (keys 0..31), nc2/3 -> chunk 1 (32..63)).
// Double-buffered K/V LDS, single barrier per tile. No-max softmax.
// K LDS swizzle: granule key*8 + (c ^ (key&7)). V^T LDS: row d = 9 granules
// (64 keys + pad), granule (d*9 + kg) ^ ((d>>3)&7) -- injective (XOR stays
// within aligned-8 blocks; row-octet footprints disjoint).
// (R4 bench attempt died infra-side: container failed twice, no error from
// compile/validate; kernel audited for OOB/LDS/hang hazards -- none found.)
// ---------------------------------------------------------------------------
__global__ __launch_bounds__(256, 3) void attn_kernel(const bf16* __restrict__ qkv,
                                                      bf16* __restrict__ o) {
  __shared__ alignas(16) bf16 Kl[2][64 * 64];  // [buf][key][d] swizzled, 16KB
  __shared__ alignas(16) bf16 Vt[2][64 * 72];  // [buf][d][key] swizzled, 18KB
  int tid = threadIdx.x;
  int lane = tid & 63, w = tid >> 6;  // w in 0..3
  int q16 = lane & 15, quad = lane >> 4;
  int b = blockIdx.y / 12, h = blockIdx.y % 12;
  int qbase = blockIdx.x * 128 + w * 32;
  const int KS = 64 * 2304;

  // Q fragments (B-operand layout n=q16, k=quad*8+j), 2 q-tiles x 2 d-chunks
  bf16x8 qf[2][2];
#pragma unroll
  for (int qt = 0; qt < 2; qt++)
#pragma unroll
    for (int c = 0; c < 2; c++)
      qf[qt][c] = *(const bf16x8*)(qkv +
          (size_t)(b * 1024 + qbase + qt * 16 + q16) * 2304 + h * 64 +
          c * 32 + quad * 8);

  // K DMA: wave w stages keys w*16..w*16+15 (two 8-key chunks); lane fetches
  // the 16B chunk that lands (lane-contiguous DMA) at swizzled granule
  // key*8 + (c ^ (key&7))
  int krow = lane >> 3;
  int kchunk = (lane & 7) ^ krow;
  const bf16* kg0 = qkv + (size_t)(b * 1024 + w * 16 + krow) * 2304 + 768 +
                    h * 64 + kchunk * 8;
  const bf16* kg1 = kg0 + 8 * 2304;
  bf16* kdA[2] = {&Kl[0][w * 1024], &Kl[1][w * 1024]};

  // V staging: thread -> key kr (tid>>2, 0..63), d-chunks dbase, dbase+8;
  // swizzled transpose writes
  int kr = tid >> 2;
  int dbase = (tid & 3) * 16;
  const bf16* vgA = qkv + (size_t)(b * 1024 + kr) * 2304 + 1536 + h * 64 + dbase;
  const bf16* vgB = vgA + 8;
  int vtA[8], vtB[8];
#pragma unroll
  for (int e = 0; e < 8; e++) {
    int dA = dbase + e;
    int dB = dbase + 8 + e;
    vtA[e] = ((dA * 9 + (kr >> 3)) ^ ((dA >> 3) & 7)) * 8 + (kr & 7);
    vtB[e] = ((dB * 9 + (kr >> 3)) ^ ((dB >> 3) & 7)) * 8 + (kr & 7);
  }

  // loop-invariant LDS read offsets
  int koff[4][2];
#pragma unroll
  for (int nc = 0; nc < 4; nc++)
#pragma unroll
    for (int ck = 0; ck < 2; ck++) {
      int key = nc * 16 + q16;
      koff[nc][ck] = (key * 8 + ((ck * 4 + quad) ^ (key & 7))) * 8;
    }
  int voff[2][4];
#pragma unroll
  for (int c = 0; c < 2; c++)
#pragma unroll
    for (int dc = 0; dc < 4; dc++) {
      int d = dc * 16 + q16;
      voff[c][dc] = ((d * 9 + (c * 4 + quad)) ^ ((d >> 3) & 7)) * 8;
    }

  int srcLo = q16 + ((quad & 1) << 5);
  int srcHi = srcLo + 16;
  bool loH = quad < 2;

  float lsum[2] = {0.f, 0.f};
  floatx4 oacc[2][4];
#pragma unroll
  for (int qt = 0; qt < 2; qt++)
#pragma unroll
    for (int dc = 0; dc < 4; dc++) oacc[qt][dc] = (floatx4){0.f, 0.f, 0.f, 0.f};

  // prologue: stage tile 0 (K-DMA + V write), prefetch V of tile 1
  GLDS16(kg0, kdA[0]);
  GLDS16(kg1, kdA[0] + 512);
  kg0 += KS; kg1 += KS;
  bf16x8 va = *(const bf16x8*)vgA;
  bf16x8 vb = *(const bf16x8*)vgB;
  vgA += KS; vgB += KS;
#pragma unroll
  for (int e = 0; e < 8; e++) Vt[0][vtA[e]] = va[e];
#pragma unroll
  for (int e = 0; e < 8; e++) Vt[0][vtB[e]] = vb[e];
  va = *(const bf16x8*)vgA;
  vb = *(const bf16x8*)vgB;
  vgA += KS; vgB += KS;

  for (int kt = 0; kt < 16; kt++) {
    int cur = kt & 1, nxt = cur ^ 1;
    __syncthreads();  // buf[cur] staged & visible; buf[nxt] free for reuse
    if (kt < 15) {
      GLDS16(kg0, kdA[nxt]);  // in flight during compute below
      GLDS16(kg1, kdA[nxt] + 512);
      kg0 += KS; kg1 += KS;
#pragma unroll
      for (int e = 0; e < 8; e++) Vt[nxt][vtA[e]] = va[e];
#pragma unroll
      for (int e = 0; e < 8; e++) Vt[nxt][vtB[e]] = vb[e];
      if (kt < 14) {
        va = *(const bf16x8*)vgA;  // prefetch V of tile kt+2
        vb = *(const bf16x8*)vgB;
        vgA += KS; vgB += KS;
      }
    }

    // QK^T (swapped): z[qt][nc][r] = S[key = nc*16 + quad*4 + r][q]
    floatx4 z[2][4];
#pragma unroll
    for (int nc = 0; nc < 4; nc++) {
      bf16x8 k0 = *(const bf16x8*)&Kl[cur][koff[nc][0]];
      bf16x8 k1 = *(const bf16x8*)&Kl[cur][koff[nc][1]];
#pragma unroll
      for (int qt = 0; qt < 2; qt++) {
        floatx4 t = (floatx4){0.f, 0.f, 0.f, 0.f};
        t = MFMA16(k0, qf[qt][0], t);
        t = MFMA16(k1, qf[qt][1], t);
        z[qt][nc] = t;
      }
    }

    bf16x8 vf[2][4];
#pragma unroll
    for (int c = 0; c < 2; c++)
#pragma unroll
      for (int dc = 0; dc < 4; dc++)
        vf[c][dc] = *(const bf16x8*)&Vt[cur][voff[c][dc]];

#pragma unroll
    for (int qt = 0; qt < 2; qt++) {
      float e_[4][4];
#pragma unroll
      for (int nc = 0; nc < 4; nc++)
#pragma unroll
        for (int r = 0; r < 4; r++) {
          e_[nc][r] = __builtin_amdgcn_exp2f(z[qt][nc][r] * 0.18033688011f);
          lsum[qt] += e_[nc][r];
        }
      int P[4][2];
#pragma unroll
      for (int nc = 0; nc < 4; nc++) {
        P[nc][0] = pack2(e_[nc][0], e_[nc][1]);
        P[nc][1] = pack2(e_[nc][2], e_[nc][3]);
      }
      union { int i[4]; bf16x8 v; } pu[2];
#pragma unroll
      for (int c = 0; c < 2; c++) {
        int a0 = __shfl(P[2 * c][0], srcLo, 64), b0 = __shfl(P[2 * c + 1][0], srcLo, 64);
        int a1 = __shfl(P[2 * c][1], srcLo, 64), b1 = __shfl(P[2 * c + 1][1], srcLo, 64);
        int a2 = __shfl(P[2 * c][0], srcHi, 64), b2 = __shfl(P[2 * c + 1][0], srcHi, 64);
        int a3 = __shfl(P[2 * c][1], srcHi, 64), b3 = __shfl(P[2 * c + 1][1], srcHi, 64);
        pu[c].i[0] = loH ? a0 : b0;
        pu[c].i[1] = loH ? a1 : b1;
        pu[c].i[2] = loH ? a2 : b2;
        pu[c].i[3] = loH ? a3 : b3;
      }
#pragma unroll
      for (int dc = 0; dc < 4; dc++) {
        oacc[qt][dc] = MFMA16(pu[0].v, vf[0][dc], oacc[qt][dc]);
        oacc[qt][dc] = MFMA16(pu[1].v, vf[1][dc], oacc[qt][dc]);
      }
    }
  }

  // final: l(q16) = sum over the 4 quads (disjoint key sets), broadcast to
  // output rows q = quad*4 + r via shfl, divide, store
#pragma unroll
  for (int qt = 0; qt < 2; qt++) {
    float s = lsum[qt];
    s += __shfl_xor(s, 16, 64);
    s += __shfl_xor(s, 32, 64);
    float inv = 1.0f / s;
    bf16* op = o + (size_t)(b * 1024 + qbase + qt * 16) * 768 + h * 64;
#pragma unroll
    for (int r = 0; r < 4; r++) {
      float invr = __shfl(inv, quad * 4 + r, 64);
#pragma unroll
      for (int dc = 0; dc < 4; dc++)
        op[(size_t)(quad * 4 + r) * 768 + dc * 16 + q16] =
            (bf16)(oacc[qt][dc][r] * invr);
    }
  }
}

// ---------------------------------------------------------------------------
extern "C" void kernel_launch(void* const* d_in, const int* in_sizes, int n_in,
                              void* d_out, int out_size, void* d_ws, size_t ws_size,
                              hipStream_t stream) {
  (void)in_sizes; (void)n_in; (void)out_size; (void)ws_size;
  const float* x      = (const float*)d_in[0];
  const float* ln1_w  = (const float*)d_in[1];
  const float* ln1_b  = (const float*)d_in[2];
  const float* qkv_w  = (const float*)d_in[3];
  const float* qkv_b  = (const float*)d_in[4];
  const float* proj_w = (const float*)d_in[5];
  const float* proj_b = (const float*)d_in[6];
  const float* ln2_w  = (const float*)d_in[7];
  const float* ln2_b  = (const float*)d_in[8];
  const float* fc1_w  = (const float*)d_in[9];
  const float* fc1_b  = (const float*)d_in[10];
  const float* fc2_w  = (const float*)d_in[11];
  const float* fc2_b  = (const float*)d_in[12];

  char* ws = (char*)d_ws;
  size_t off = 0;
  auto alloc = [&](size_t bytes) {
    void* p = ws + off;
    off += (bytes + 255) & ~(size_t)255;
    return p;
  };
  bf16* wq  = (bf16*)alloc((size_t)2304 * 768 * 2);
  bf16* wp  = (bf16*)alloc((size_t)768 * 768 * 2);
  bf16* wf1 = (bf16*)alloc((size_t)3072 * 768 * 2);
  bf16* wf2 = (bf16*)alloc((size_t)768 * 3072 * 2);
  bf16* slotA = (bf16*)alloc((size_t)8192 * 768 * 2);   // h1 / ob / h2
  bf16* slotB = (bf16*)alloc((size_t)8192 * 3072 * 2);  // qkv / fc1-out
  float* x1 = (float*)alloc((size_t)8192 * 768 * 4);

  bf16* h1 = slotA;
  bf16* qkvb = slotB;
  bf16* ob = slotA;
  bf16* h2 = slotA;
  bf16* hm = slotB;

  pre_kernel<<<8192 + 6912, 256, 0, stream>>>(
      x, ln1_w, ln1_b, h1,
      qkv_w, wq, 2304 * 768 / 4, proj_w, wp, 768 * 768 / 4,
      fc1_w, wf1, 3072 * 768 / 4, fc2_w, wf2, 768 * 3072 / 4);

  gemm_bt<EP_BF16, 4><<<dim3(18, 64), 256, 0, stream>>>(
      h1, wq, qkv_b, nullptr, qkvb, 8192, 2304, 768);
  attn_kernel<<<dim3(8, 96), 256, 0, stream>>>(qkvb, ob);
  gemm_bt<EP_RES_F32, 2><<<dim3(12, 64), 256, 0, stream>>>(
      ob, wp, proj_b, x, x1, 8192, 768, 768);
  ln_kernel<<<8192, 256, 0, stream>>>(x1, ln2_w, ln2_b, h2);
  gemm_bt<EP_GELU_BF16, 4><<<dim3(24, 64), 256, 0, stream>>>(
      h2, wf1, fc1_b, nullptr, hm, 8192, 3072, 768);
  gemm_bt<EP_RES_F32, 2><<<dim3(12, 64), 256, 0, stream>>>(
      hm, wf2, fc2_b, x1, (float*)d_out, 8192, 768, 3072);
}

// Round 6
// 326.091 us; speedup vs baseline: 1.1297x; 1.0530x over previous
//
#include <hip/hip_runtime.h>
#include <cmath>

typedef __bf16 bf16;
typedef __bf16 bf16x8 __attribute__((ext_vector_type(8)));
typedef __bf16 bf16x4 __attribute__((ext_vector_type(4)));
typedef __bf16 bf16x2 __attribute__((ext_vector_type(2)));
typedef float floatx4 __attribute__((ext_vector_type(4)));
typedef unsigned int uint;

#define MFMA16(A, B, C) __builtin_amdgcn_mfma_f32_16x16x32_bf16((A), (B), (C), 0, 0, 0)

// async 16B/lane global->LDS (lds dest = wave-uniform base + lane*16)
#define GLDS16(g, l)                                                   \
  __builtin_amdgcn_global_load_lds(                                    \
      (const __attribute__((address_space(1))) void*)(g),              \
      (__attribute__((address_space(3))) void*)(l), 16, 0, 0)

static __device__ __forceinline__ int pack2(float a, float b) {
  bf16x2 t;
  t[0] = (bf16)a;
  t[1] = (bf16)b;
  return __builtin_bit_cast(int, t);
}

// ---------------------------------------------------------------------------
// fused: LN1 (blocks 0..8191) + fp32->bf16 weight convert (blocks 8192..)
// ---------------------------------------------------------------------------
__global__ __launch_bounds__(256) void pre_kernel(
    const float* __restrict__ x, const float* __restrict__ g,
    const float* __restrict__ be, bf16* __restrict__ h1,
    const float* __restrict__ s0, bf16* __restrict__ d0, int n0,
    const float* __restrict__ s1, bf16* __restrict__ d1, int n1,
    const float* __restrict__ s2, bf16* __restrict__ d2, int n2,
    const float* __restrict__ s3, bf16* __restrict__ d3, int n3) {
  int bid = blockIdx.x;
  int t = threadIdx.x;
  if (bid < 8192) {
    const float* xr = x + (size_t)bid * 768;
    float v0 = xr[t], v1 = xr[t + 256], v2 = xr[t + 512];
    float s = v0 + v1 + v2;
    float s2 = v0 * v0 + v1 * v1 + v2 * v2;
#pragma unroll
    for (int o = 1; o < 64; o <<= 1) {
      s += __shfl_xor(s, o, 64);
      s2 += __shfl_xor(s2, o, 64);
    }
    __shared__ float red[8];
    int w = t >> 6, lane = t & 63;
    if (lane == 0) { red[w] = s; red[4 + w] = s2; }
    __syncthreads();
    float ts = red[0] + red[1] + red[2] + red[3];
    float ts2 = red[4] + red[5] + red[6] + red[7];
    float mean = ts * (1.0f / 768.0f);
    float var = ts2 * (1.0f / 768.0f) - mean * mean;
    float rstd = rsqrtf(var + 1e-5f);
    bf16* orow = h1 + (size_t)bid * 768;
    orow[t]       = (bf16)((v0 - mean) * rstd * g[t]       + be[t]);
    orow[t + 256] = (bf16)((v1 - mean) * rstd * g[t + 256] + be[t + 256]);
    orow[t + 512] = (bf16)((v2 - mean) * rstd * g[t + 512] + be[t + 512]);
    return;
  }
  int i = (bid - 8192) * 256 + t;
  const float* s;
  bf16* d;
  if (i < n0) { s = s0 + (size_t)i * 4; d = d0 + (size_t)i * 4; }
  else if ((i -= n0) < n1) { s = s1 + (size_t)i * 4; d = d1 + (size_t)i * 4; }
  else if ((i -= n1) < n2) { s = s2 + (size_t)i * 4; d = d2 + (size_t)i * 4; }
  else if ((i -= n2) < n3) { s = s3 + (size_t)i * 4; d = d3 + (size_t)i * 4; }
  else return;
  bf16x4 v;
  v[0] = (bf16)s[0]; v[1] = (bf16)s[1]; v[2] = (bf16)s[2]; v[3] = (bf16)s[3];
  *(bf16x4*)d = v;
}

// ---------------------------------------------------------------------------
// LayerNorm over C=768, fp32 in -> bf16 out (x1 -> h2)
// ---------------------------------------------------------------------------
__global__ __launch_bounds__(256) void ln_kernel(const float* __restrict__ x,
                                                 const float* __restrict__ g,
                                                 const float* __restrict__ be,
                                                 bf16* __restrict__ out) {
  int row = blockIdx.x;
  int t = threadIdx.x;
  const float* xr = x + (size_t)row * 768;
  float v0 = xr[t], v1 = xr[t + 256], v2 = xr[t + 512];
  float s = v0 + v1 + v2;
  float s2 = v0 * v0 + v1 * v1 + v2 * v2;
#pragma unroll
  for (int o = 1; o < 64; o <<= 1) {
    s += __shfl_xor(s, o, 64);
    s2 += __shfl_xor(s2, o, 64);
  }
  __shared__ float red[8];
  int w = t >> 6, lane = t & 63;
  if (lane == 0) { red[w] = s; red[4 + w] = s2; }
  __syncthreads();
  float ts = red[0] + red[1] + red[2] + red[3];
  float ts2 = red[4] + red[5] + red[6] + red[7];
  float mean = ts * (1.0f / 768.0f);
  float var = ts2 * (1.0f / 768.0f) - mean * mean;
  float rstd = rsqrtf(var + 1e-5f);
  bf16* orow = out + (size_t)row * 768;
  orow[t]       = (bf16)((v0 - mean) * rstd * g[t]       + be[t]);
  orow[t + 256] = (bf16)((v1 - mean) * rstd * g[t + 256] + be[t + 256]);
  orow[t + 512] = (bf16)((v2 - mean) * rstd * g[t + 512] + be[t + 512]);
}

// ---------------------------------------------------------------------------
// GEMM: C[m,n] = sum_k A[m,k]*B[n,k] (+bias)  (A:[M,K] bf16, B:[N,K] bf16)
// 128 x (32*NJ) tile, 4 waves, templated BK (64 or 128), global_load_lds
// width=16 into XOR-granule-swizzled rows (slot s of row r holds k-granule
// s ^ (r & (GR-1)), GR = BK/8 granules/row). 2-barrier K-loop (measured best
// vs dbuf R1 / counted-vmcnt R3). BK=128 for NJ=2 (48 KB LDS, still 3
// blocks/CU) halves the per-step barrier drains (fc2: 48 -> 24 steps) --
// R3 showed barrier count is the sensitivity (2x barriers -> +35%).
// XCD swizzle: flat%8 = m-stripe, n fastest.
// EP_RES_F32: out = acc + bias + resid (f32) -- used with NJ=2 for N=768.
// ---------------------------------------------------------------------------
constexpr int EP_BF16 = 0;
constexpr int EP_RES_F32 = 1;
constexpr int EP_GELU_BF16 = 2;

template <int EP, int NJ, int BK>
__global__ __launch_bounds__(256, 3) void gemm_bt(
    const bf16* __restrict__ A, const bf16* __restrict__ Bw,
    const float* __restrict__ bias, const float* __restrict__ resid,
    void* __restrict__ outp, int M, int N, int K) {
  constexpr int GR = BK / 8;               // granules per row
  constexpr int RC = 64 / GR;              // rows per 1024B DMA chunk
  constexpr int ACH = 128 / RC / 4;        // A chunks per wave
  constexpr int BCH = (32 * NJ) / RC / 4;  // B chunks per wave
  constexpr int NKS = BK / 32;             // 32-deep MFMA steps per K-step
  __shared__ alignas(16) bf16 Asl[128 * BK];
  __shared__ alignas(16) bf16 Bsl[NJ * 32 * BK];
  int tid = threadIdx.x;
  int lane = tid & 63, w = tid >> 6;
  int wm = w >> 1, wn = w & 1;
  int q16 = lane & 15, quad = lane >> 4;
  int fid = blockIdx.x + gridDim.x * blockIdx.y;
  int nb = gridDim.x;
  int s = fid >> 3;
  int m0 = ((fid & 7) * (gridDim.y >> 3) + s / nb) * 128;
  int n0 = (s % nb) * (NJ * 32);

  floatx4 acc[4][NJ];
#pragma unroll
  for (int i = 0; i < 4; i++)
#pragma unroll
    for (int j = 0; j < NJ; j++) acc[i][j] = (floatx4){0.f, 0.f, 0.f, 0.f};

  // staging: lane L of chunk c -> row c*RC + L/GR, slot L&(GR-1); slot s of
  // row r must hold global k-granule s ^ (r&(GR-1))
  int rIn = lane / GR;
  int sl = lane & (GR - 1);
  const bf16* ag[ACH];
  const bf16* bg[BCH];
#pragma unroll
  for (int q = 0; q < ACH; q++) {
    int row = (w * ACH + q) * RC + rIn;
    ag[q] = A + (size_t)(m0 + row) * K + (size_t)(sl ^ (row & (GR - 1))) * 8;
  }
#pragma unroll
  for (int q = 0; q < BCH; q++) {
    int row = (w * BCH + q) * RC + rIn;
    bg[q] = Bw + (size_t)(n0 + row) * K + (size_t)(sl ^ (row & (GR - 1))) * 8;
  }
  bf16* la = &Asl[w * ACH * 512];
  bf16* lb = &Bsl[w * BCH * 512];

  // frag read offsets: row*BK + ((ks*4+quad) ^ (row&(GR-1)))*8; frag row
  // & (GR-1) always reduces to q16&(GR-1) (other terms are 0 mod GR)
  int swz = q16 & (GR - 1);
  int offA[NKS][4], offB[NKS][NJ];
#pragma unroll
  for (int ks = 0; ks < NKS; ks++) {
#pragma unroll
    for (int i = 0; i < 4; i++)
      offA[ks][i] = (wm * 64 + i * 16 + q16) * BK + ((ks * 4 + quad) ^ swz) * 8;
#pragma unroll
    for (int j = 0; j < NJ; j++)
      offB[ks][j] = (wn * 16 * NJ + j * 16 + q16) * BK + ((ks * 4 + quad) ^ swz) * 8;
  }

  for (int k0 = 0; k0 < K; k0 += BK) {
    __syncthreads();
#pragma unroll
    for (int q = 0; q < ACH; q++) {
      GLDS16(ag[q], la + q * 512);
      ag[q] += BK;
    }
#pragma unroll
    for (int q = 0; q < BCH; q++) {
      GLDS16(bg[q], lb + q * 512);
      bg[q] += BK;
    }
    __syncthreads();
#pragma unroll
    for (int ks = 0; ks < NKS; ks++) {
      bf16x8 af[4], bfr[NJ];
#pragma unroll
      for (int i = 0; i < 4; i++) af[i] = *(const bf16x8*)&Asl[offA[ks][i]];
#pragma unroll
      for (int j = 0; j < NJ; j++) bfr[j] = *(const bf16x8*)&Bsl[offB[ks][j]];
#pragma unroll
      for (int i = 0; i < 4; i++)
#pragma unroll
        for (int j = 0; j < NJ; j++) acc[i][j] = MFMA16(af[i], bfr[j], acc[i][j]);
    }
  }

  // epilogue: C/D layout col = lane&15, row = quad*4 + reg  [m89-verified]
#pragma unroll
  for (int i = 0; i < 4; i++) {
#pragma unroll
    for (int j = 0; j < NJ; j++) {
#pragma unroll
      for (int r = 0; r < 4; r++) {
        int m = m0 + wm * 64 + i * 16 + quad * 4 + r;
        int n = n0 + wn * 16 * NJ + j * 16 + q16;
        size_t idx = (size_t)m * N + n;
        float v = acc[i][j][r] + bias[n];
        if constexpr (EP == EP_BF16) {
          ((bf16*)outp)[idx] = (bf16)v;
        } else if constexpr (EP == EP_RES_F32) {
          ((float*)outp)[idx] = v + resid[idx];
        } else {
          // gelu(v) = v * sigmoid(1.59577(v + 0.044715 v^3)); exp2 form
          float u = v * (2.3022083f + 0.1029443f * v * v);
          float e = __builtin_amdgcn_exp2f(-u);
          float gv = v * __builtin_amdgcn_rcpf(1.0f + e);
          ((bf16*)outp)[idx] = (bf16)gv;
        }
      }
    }
  }
}

// ---------------------------------------------------------------------------
// Flash attention, bf16 MFMA. qkv: [B,N,3,12,64] bf16 -> out [B,N,768] bf16.
// R6: attn is LDS-PIPE-bound (~60% est: 16 scalar V-writes + 16 b128 reads +
// 32 ds_bpermute(shfl) per wave-tile; MfmaUtil 16 / VALU 30 both low across
// three flat variants). Changes:
//  (1) grid transposed to (bh=96, qb=8): flat%8 = bh%8 -> all 8 q-blocks of
//      one (b,h) share an XCD; 12 bh x 256KB = 3MB fits 4MB L2 -> K/V HBM
//      fetch ~1x instead of ~4x (FETCH 109MB -> ~40MB predicted).
//  (2) V staging: 4x global b64 loads + in-reg 4x4 transpose (VALU) +
//      4x ds_write_b64 -- replaces 16x ds_write_b16 (LDS ops 16->4/thread).
//      Same swizzled V^T layout; read offsets identical to R5 (verified).
// KVBLK=64, 4-wave blocks, in-reg P via swapped QK^T, dbuf K/V LDS, single
// barrier per tile, no-max softmax (|s| small, shift-invariant).
// ---------------------------------------------------------------------------
__global__ __launch_bounds__(256, 3) void attn_kernel(const bf16* __restrict__ qkv,
                                                      bf16* __restrict__ o) {
  __shared__ alignas(16) bf16 Kl[2][64 * 64];  // [buf][key][d] swizzled, 16KB
  __shared__ alignas(16) bf16 Vt[2][64 * 72];  // [buf][d][key] swizzled, 18KB
  int tid = threadIdx.x;
  int lane = tid & 63, w = tid >> 6;  // w in 0..3
  int q16 = lane & 15, quad = lane >> 4;
  int b = blockIdx.x / 12, h = blockIdx.x % 12;   // bh on x: XCD-local K/V
  int qbase = blockIdx.y * 128 + w * 32;
  const int KS = 64 * 2304;

  // Q fragments (B-operand layout n=q16, k=quad*8+j), 2 q-tiles x 2 d-chunks
  bf16x8 qf[2][2];
#pragma unroll
  for (int qt = 0; qt < 2; qt++)
#pragma unroll
    for (int c = 0; c < 2; c++)
      qf[qt][c] = *(const bf16x8*)(qkv +
          (size_t)(b * 1024 + qbase + qt * 16 + q16) * 2304 + h * 64 +
          c * 32 + quad * 8);

  // K DMA: wave w stages keys w*16..w*16+15 (two 8-key chunks); lane fetches
  // the 16B chunk that lands (lane-contiguous DMA) at swizzled granule
  // key*8 + (c ^ (key&7))
  int krow = lane >> 3;
  int kchunk = (lane & 7) ^ krow;
  const bf16* kg0 = qkv + (size_t)(b * 1024 + w * 16 + krow) * 2304 + 768 +
                    h * 64 + kchunk * 8;
  const bf16* kg1 = kg0 + 8 * 2304;
  bf16* kdA[2] = {&Kl[0][w * 1024], &Kl[1][w * 1024]};

  // V staging: thread (kg = tid>>4, dg = tid&15): global b64 loads of
  // V[4kg+i][4dg..4dg+3], in-reg 4x4 transpose, 4x ds_write_b64 into the
  // swizzled V^T: elem (d,key) at granule (d*9 + (key>>3)) ^ ((d>>3)&7),
  // sub-elem key&7. Keys 4kg..4kg+3 are granule-half-aligned -> one b64.
  int kg = tid >> 4;
  int dg = tid & 15;
  const bf16* vgp = qkv + (size_t)(b * 1024 + 4 * kg) * 2304 + 1536 + h * 64 +
                    4 * dg;
  int vw[4];
#pragma unroll
  for (int j = 0; j < 4; j++) {
    int d = 4 * dg + j;
    vw[j] = (((d * 9 + (kg >> 1)) ^ ((d >> 3) & 7)) * 8) + (kg & 1) * 4;
  }
  uint2 vr[4];

  // loop-invariant LDS read offsets
  int koff[4][2];
#pragma unroll
  for (int nc = 0; nc < 4; nc++)
#pragma unroll
    for (int ck = 0; ck < 2; ck++) {
      int key = nc * 16 + q16;
      koff[nc][ck] = (key * 8 + ((ck * 4 + quad) ^ (key & 7))) * 8;
    }
  int voff[2][4];
#pragma unroll
  for (int c = 0; c < 2; c++)
#pragma unroll
    for (int dc = 0; dc < 4; dc++) {
      int d = dc * 16 + q16;
      voff[c][dc] = ((d * 9 + (c * 4 + quad)) ^ ((d >> 3) & 7)) * 8;
    }

  int srcLo = q16 + ((quad & 1) << 5);
  int srcHi = srcLo + 16;
  bool loH = quad < 2;

  float lsum[2] = {0.f, 0.f};
  floatx4 oacc[2][4];
#pragma unroll
  for (int qt = 0; qt < 2; qt++)
#pragma unroll
    for (int dc = 0; dc < 4; dc++) oacc[qt][dc] = (floatx4){0.f, 0.f, 0.f, 0.f};

#define VLOAD()                                                        \
  do {                                                                 \
    _Pragma("unroll") for (int i = 0; i < 4; i++)                      \
        vr[i] = *(const uint2*)(vgp + i * 2304);                       \
    vgp += KS;                                                         \
  } while (0)

#define VWRITE(buf)                                                    \
  do {                                                                 \
    uint lo0 = vr[0].x, lo1 = vr[1].x, lo2 = vr[2].x, lo3 = vr[3].x;   \
    uint hi0 = vr[0].y, hi1 = vr[1].y, hi2 = vr[2].y, hi3 = vr[3].y;   \
    uint2 c0, c1, c2, c3;                                              \
    c0.x = (lo0 & 0xFFFFu) | (lo1 << 16);                              \
    c0.y = (lo2 & 0xFFFFu) | (lo3 << 16);                              \
    c1.x = (lo0 >> 16) | (lo1 & 0xFFFF0000u);                          \
    c1.y = (lo2 >> 16) | (lo3 & 0xFFFF0000u);                          \
    c2.x = (hi0 & 0xFFFFu) | (hi1 << 16);                              \
    c2.y = (hi2 & 0xFFFFu) | (hi3 << 16);                              \
    c3.x = (hi0 >> 16) | (hi1 & 0xFFFF0000u);                          \
    c3.y = (hi2 >> 16) | (hi3 & 0xFFFF0000u);                          \
    *(uint2*)&Vt[buf][vw[0]] = c0;                                     \
    *(uint2*)&Vt[buf][vw[1]] = c1;                                     \
    *(uint2*)&Vt[buf][vw[2]] = c2;                                     \
    *(uint2*)&Vt[buf][vw[3]] = c3;                                     \
  } while (0)

  // prologue: stage tile 0 (K-DMA + V write), prefetch V of tile 1 into regs
  GLDS16(kg0, kdA[0]);
  GLDS16(kg1, kdA[0] + 512);
  kg0 += KS; kg1 += KS;
  VLOAD();
  VWRITE(0);
  VLOAD();

  for (int kt = 0; kt < 16; kt++) {
    int cur = kt & 1, nxt = cur ^ 1;
    __syncthreads();  // buf[cur] staged & visible; buf[nxt] free for reuse
    if (kt < 15) {
      GLDS16(kg0, kdA[nxt]);  // in flight during compute below
      GLDS16(kg1, kdA[nxt] + 512);
      kg0 += KS; kg1 += KS;
      VWRITE(nxt);
      if (kt < 14) VLOAD();  // prefetch V of tile kt+2
    }

    // QK^T (swapped): z[qt][nc][r] = S[key = nc*16 + quad*4 + r][q]
    floatx4 z[2][4];
#pragma unroll
    for (int nc = 0; nc < 4; nc++) {
      bf16x8 k0 = *(const bf16x8*)&Kl[cur][koff[nc][0]];
      bf16x8 k1 = *(const bf16x8*)&Kl[cur][koff[nc][1]];
#pragma unroll
      for (int qt = 0; qt < 2; qt++) {
        floatx4 t = (floatx4){0.f, 0.f, 0.f, 0.f};
        t = MFMA16(k0, qf[qt][0], t);
        t = MFMA16(k1, qf[qt][1], t);
        z[qt][nc] = t;
      }
    }

    bf16x8 vf[2][4];
#pragma unroll
    for (int c = 0; c < 2; c++)
#pragma unroll
      for (int dc = 0; dc < 4; dc++)
        vf[c][dc] = *(const bf16x8*)&Vt[cur][voff[c][dc]];

#pragma unroll
    for (int qt = 0; qt < 2; qt++) {
      float e_[4][4];
#pragma unroll
      for (int nc = 0; nc < 4; nc++)
#pragma unroll
        for (int r = 0; r < 4; r++) {
          e_[nc][r] = __builtin_amdgcn_exp2f(z[qt][nc][r] * 0.18033688011f);
          lsum[qt] += e_[nc][r];
        }
      int P[4][2];
#pragma unroll
      for (int nc = 0; nc < 4; nc++) {
        P[nc][0] = pack2(e_[nc][0], e_[nc][1]);
        P[nc][1] = pack2(e_[nc][2], e_[nc][3]);
      }
      union { int i[4]; bf16x8 v; } pu[2];
#pragma unroll
      for (int c = 0; c < 2; c++) {
        int a0 = __shfl(P[2 * c][0], srcLo, 64), b0 = __shfl(P[2 * c + 1][0], srcLo, 64);
        int a1 = __shfl(P[2 * c][1], srcLo, 64), b1 = __shfl(P[2 * c + 1][1], srcLo, 64);
        int a2 = __shfl(P[2 * c][0], srcHi, 64), b2 = __shfl(P[2 * c + 1][0], srcHi, 64);
        int a3 = __shfl(P[2 * c][1], srcHi, 64), b3 = __shfl(P[2 * c + 1][1], srcHi, 64);
        pu[c].i[0] = loH ? a0 : b0;
        pu[c].i[1] = loH ? a1 : b1;
        pu[c].i[2] = loH ? a2 : b2;
        pu[c].i[3] = loH ? a3 : b3;
      }
#pragma unroll
      for (int dc = 0; dc < 4; dc++) {
        oacc[qt][dc] = MFMA16(pu[0].v, vf[0][dc], oacc[qt][dc]);
        oacc[qt][dc] = MFMA16(pu[1].v, vf[1][dc], oacc[qt][dc]);
      }
    }
  }

  // final: l(q16) = sum over the 4 quads (disjoint key sets), broadcast to
  // output rows q = quad*4 + r via shfl, divide, store
#pragma unroll
  for (int qt = 0; qt < 2; qt++) {
    float s = lsum[qt];
    s += __shfl_xor(s, 16, 64);
    s += __shfl_xor(s, 32, 64);
    float inv = 1.0f / s;
    bf16* op = o + (size_t)(b * 1024 + qbase + qt * 16) * 768 + h * 64;
#pragma unroll
    for (int r = 0; r < 4; r++) {
      float invr = __shfl(inv, quad * 4 + r, 64);
#pragma unroll
      for (int dc = 0; dc < 4; dc++)
        op[(size_t)(quad * 4 + r) * 768 + dc * 16 + q16] =
            (bf16)(oacc[qt][dc][r] * invr);
    }
  }
#undef VLOAD
#undef VWRITE
}

// ---------------------------------------------------------------------------
extern "C" void kernel_launch(void* const* d_in, const int* in_sizes, int n_in,
                              void* d_out, int out_size, void* d_ws, size_t ws_size,
                              hipStream_t stream) {
  (void)in_sizes; (void)n_in; (void)out_size; (void)ws_size;
  const float* x      = (const float*)d_in[0];
  const float* ln1_w  = (const float*)d_in[1];
  const float* ln1_b  = (const float*)d_in[2];
  const float* qkv_w  = (const float*)d_in[3];
  const float* qkv_b  = (const float*)d_in[4];
  const float* proj_w = (const float*)d_in[5];
  const float* proj_b = (const float*)d_in[6];
  const float* ln2_w  = (const float*)d_in[7];
  const float* ln2_b  = (const float*)d_in[8];
  const float* fc1_w  = (const float*)d_in[9];
  const float* fc1_b  = (const float*)d_in[10];
  const float* fc2_w  = (const float*)d_in[11];
  const float* fc2_b  = (const float*)d_in[12];

  char* ws = (char*)d_ws;
  size_t off = 0;
  auto alloc = [&](size_t bytes) {
    void* p = ws + off;
    off += (bytes + 255) & ~(size_t)255;
    return p;
  };
  bf16* wq  = (bf16*)alloc((size_t)2304 * 768 * 2);
  bf16* wp  = (bf16*)alloc((size_t)768 * 768 * 2);
  bf16* wf1 = (bf16*)alloc((size_t)3072 * 768 * 2);
  bf16* wf2 = (bf16*)alloc((size_t)768 * 3072 * 2);
  bf16* slotA = (bf16*)alloc((size_t)8192 * 768 * 2);   // h1 / ob / h2
  bf16* slotB = (bf16*)alloc((size_t)8192 * 3072 * 2);  // qkv / fc1-out
  float* x1 = (float*)alloc((size_t)8192 * 768 * 4);

  bf16* h1 = slotA;
  bf16* qkvb = slotB;
  bf16* ob = slotA;
  bf16* h2 = slotA;
  bf16* hm = slotB;

  pre_kernel<<<8192 + 6912, 256, 0, stream>>>(
      x, ln1_w, ln1_b, h1,
      qkv_w, wq, 2304 * 768 / 4, proj_w, wp, 768 * 768 / 4,
      fc1_w, wf1, 3072 * 768 / 4, fc2_w, wf2, 768 * 3072 / 4);

  gemm_bt<EP_BF16, 4, 64><<<dim3(18, 64), 256, 0, stream>>>(
      h1, wq, qkv_b, nullptr, qkvb, 8192, 2304, 768);
  attn_kernel<<<dim3(96, 8), 256, 0, stream>>>(qkvb, ob);
  gemm_bt<EP_RES_F32, 2, 128><<<dim3(12, 64), 256, 0, stream>>>(
      ob, wp, proj_b, x, x1, 8192, 768, 768);
  ln_kernel<<<8192, 256, 0, stream>>>(x1, ln2_w, ln2_b, h2);
  gemm_bt<EP_GELU_BF16, 4, 64><<<dim3(24, 64), 256, 0, stream>>>(
      h2, wf1, fc1_b, nullptr, hm, 8192, 3072, 768);
  gemm_bt<EP_RES_F32, 2, 128><<<dim3(12, 64), 256, 0, stream>>>(
      hm, wf2, fc2_b, x1, (float*)d_out, 8192, 768, 3072);
}